// Round 12
// baseline (879.865 us; speedup 1.0000x reference)
//
#include <hip/hip_runtime.h>

// MPNN encoder, MI355X — round 12 (= round 11 resubmitted; infra failure, the
// kernel never ran).
// Round-10: LDS union halved edge LDS but dur unchanged (81us) — occupancy was
// NOT the limiter. Diagnosis: per-block critical path — 4 barriers (2 of them
// drain atomic vmcnt, ~900cy each) + serial 16-step LDS reduce loops. Fix:
// replace the whole mld/slds cross-wave reduce with an in-register 16-lane
// segmented shuffle scan over the sorted sources (MFMA D-frag: col=edge,
// rows=channels). Edge kernel now has ZERO barriers, no mld/slds; boundary
// atomics only (same 16-edge window granularity -> WRITE unchanged).
//
//  - edge_feat / GRU_e dead w.r.t. output -> skipped.
//  - layer1 factorized: h1 = relu(u[s] + v[d] + dpos.W1p + b1).
//  - edge L2,L3 + node GRU/proj on MFMA (bf16 operands, f32 accum).

#define NN      50000
#define NE      800000
#define NE2     (2 * NE)
#define NCLS    16
#define NBLK    196                               // ceil(NN/256)

typedef short s8v __attribute__((ext_vector_type(8)));   // 8 bf16 (4 VGPRs)
typedef float f4v __attribute__((ext_vector_type(4)));   // MFMA C/D
typedef unsigned short u16;

__device__ __forceinline__ unsigned rne16(float f) {     // f32 -> bf16 bits (RNE)
    unsigned u = __float_as_uint(f);
    return (u + 0x7FFFu + ((u >> 16) & 1u)) >> 16;
}
__device__ __forceinline__ unsigned pkbf(float lo, float hi) {
    return rne16(lo) | (rne16(hi) << 16);
}
__device__ __forceinline__ s8v pack8(const float* f) {
    s8v r;
#pragma unroll
    for (int i = 0; i < 8; ++i) r[i] = (short)rne16(f[i]);
    return r;
}
__device__ __forceinline__ float gru1(float gr, float gz, float gin, float ghn,
                                      float h) {
    float r  = __builtin_amdgcn_rcpf(1.0f + __expf(-gr));
    float z  = __builtin_amdgcn_rcpf(1.0f + __expf(-gz));
    float pre = fmaf(r, ghn, gin);
    float nj = 1.0f - 2.0f * __builtin_amdgcn_rcpf(1.0f + __expf(2.0f * pre));
    return fmaf(z, h - nj, nj);                   // (1-z)*n + z*h
}

// ---------------- prep: bg, W1p, bf16 Wg and bf16 proj weights ----------------
__global__ __launch_bounds__(256) void prep_kernel(
    const float* __restrict__ Wih, const float* __restrict__ Whh,
    const float* __restrict__ bih, const float* __restrict__ bhh,
    const float* __restrict__ W1, const float* __restrict__ b1,
    u16* __restrict__ Wg_bf, float* __restrict__ bg, float* __restrict__ W1p,
    u16* __restrict__ Wp_bf)
{
    int idx = blockIdx.x * 256 + threadIdx.x;
    if (idx < 8192) {
        int o = idx >> 6, k = idx & 63;
        float val;
        if (o < 64) {
            val = (k < 32) ? Wih[o * 32 + k] : Whh[o * 32 + (k - 32)];
        } else if (o < 96) {
            val = (k < 32) ? Wih[o * 32 + k] : 0.0f;
        } else {
            val = (k >= 32) ? Whh[(o - 32) * 32 + (k - 32)] : 0.0f;
        }
        Wg_bf[idx] = (u16)rne16(val);
    } else if (idx < 8320) {
        int i = idx - 8192;
        float val;
        if (i < 64)       val = bih[i] + bhh[i];
        else if (i < 96)  val = bih[i];
        else              val = bhh[i - 32];
        bg[i] = val;
    } else if (idx < 8448) {
        int t = idx - 8320;                    // W1p[j][c]: wx,wy,wz,b1
        int j = t >> 2, c = t & 3;
        W1p[t] = (c < 3) ? W1[j * 67 + 64 + c] : b1[j];
    } else if (idx < 10496) {
        int t = idx - 8448;                    // Wp_bf[r][k]
        int r = t >> 5, k = t & 31;
        float val = (r < 32) ? W1[r * 67 + k] : W1[(r - 32) * 67 + 32 + k];
        Wp_bf[t] = (u16)rne16(val);
    }
}

// ---------------- sort: rank-histogram, 3-kernel scan, scatter ----------------
__global__ __launch_bounds__(256) void hist_rank_kernel(
    const int* __restrict__ e0, const int* __restrict__ e1,
    int* __restrict__ deg, int* __restrict__ rank)
{
    int e = blockIdx.x * 256 + threadIdx.x;   // grid exactly NE2/256
    int s = (e < NE) ? e0[e] : e1[e - NE];
    rank[e] = atomicAdd(&deg[s], 1);          // rank store is coalesced
}

__global__ __launch_bounds__(256) void scan_part_kernel(
    const int* __restrict__ deg, int* __restrict__ bsum)
{
    int t = blockIdx.x * 256 + threadIdx.x;
    int x = (t < NN) ? deg[t] : 0;
#pragma unroll
    for (int off = 1; off < 64; off <<= 1) x += __shfl_xor(x, off);
    __shared__ int wsum[4];
    if ((threadIdx.x & 63) == 0) wsum[threadIdx.x >> 6] = x;
    __syncthreads();
    if (threadIdx.x == 0)
        bsum[blockIdx.x] = wsum[0] + wsum[1] + wsum[2] + wsum[3];
}

__global__ __launch_bounds__(256) void scan_mid_kernel(
    const int* __restrict__ bsum, int* __restrict__ boff, int* __restrict__ rowptr)
{
    __shared__ int sd[256];
    int t = threadIdx.x;
    int x = (t < NBLK) ? bsum[t] : 0;
    sd[t] = x;
    __syncthreads();
    for (int off = 1; off < 256; off <<= 1) {
        int vv = (t >= off) ? sd[t - off] : 0;
        __syncthreads();
        sd[t] += vv;
        __syncthreads();
    }
    if (t < NBLK) boff[t] = sd[t] - x;         // exclusive block offsets
    if (t == 0) rowptr[NN] = NE2;              // total degree is constant
}

__global__ __launch_bounds__(256) void scan_apply_kernel(
    const int* __restrict__ deg, const int* __restrict__ boff,
    int* __restrict__ rowptr)
{
    __shared__ int sd[256];
    int tid = threadIdx.x;
    int t = blockIdx.x * 256 + tid;
    int x = (t < NN) ? deg[t] : 0;
    sd[tid] = x;
    __syncthreads();
    for (int off = 1; off < 256; off <<= 1) {
        int vv = (tid >= off) ? sd[tid - off] : 0;
        __syncthreads();
        sd[tid] += vv;
        __syncthreads();
    }
    if (t < NN) rowptr[t] = boff[blockIdx.x] + sd[tid] - x;   // exclusive
}

__global__ __launch_bounds__(256) void scatter_kernel(
    const int* __restrict__ e0, const int* __restrict__ e1,
    const int* __restrict__ rowptr, const int* __restrict__ rank,
    int2* __restrict__ sd)
{
    int e = blockIdx.x * 256 + threadIdx.x;   // grid exactly NE2/256
    int s, d;
    if (e < NE) { s = e0[e]; d = e1[e]; }
    else        { s = e1[e - NE]; d = e0[e - NE]; }
    int p = rowptr[s] + rank[e];
    sd[p] = make_int2(s, d);                  // single scattered 8B store
}

// ---------------- u,v projection (init only, f32) ----------------
__device__ __forceinline__ void proj_uv(const float nn[32], int n,
                                        const float* __restrict__ W1,
                                        float* __restrict__ u, float* __restrict__ v)
{
    for (int j = 0; j < 32; ++j) {            // rolled: W1 addrs uniform -> s_load
        float su = 0.0f, sv = 0.0f;
#pragma unroll
        for (int k = 0; k < 32; ++k) {
            su = fmaf(W1[j * 67 + k],      nn[k], su);
            sv = fmaf(W1[j * 67 + 32 + k], nn[k], sv);
        }
        u[(size_t)n * 32 + j] = su;
        v[(size_t)n * 32 + j] = sv;
    }
}

// ---------------- init: node = classes@W_in.T + b_in; emit u,v; zero acc ------
__global__ __launch_bounds__(256) void init_kernel(
    const float* __restrict__ classes, const float* __restrict__ W_in,
    const float* __restrict__ b_in, const float* __restrict__ W1,
    float* __restrict__ node, float* __restrict__ u, float* __restrict__ v,
    float* __restrict__ acc)
{
    int n = blockIdx.x * 256 + threadIdx.x;
    if (n >= NN) return;

    float cls[16];
    const float4* cr = reinterpret_cast<const float4*>(classes + (size_t)n * NCLS);
#pragma unroll
    for (int q = 0; q < 4; ++q) {
        float4 c4 = cr[q];
        cls[q * 4 + 0] = c4.x; cls[q * 4 + 1] = c4.y;
        cls[q * 4 + 2] = c4.z; cls[q * 4 + 3] = c4.w;
    }

    float nn[32];
#pragma unroll
    for (int j = 0; j < 32; ++j) {
        float t = b_in[j];
#pragma unroll
        for (int k = 0; k < 16; ++k) t = fmaf(W_in[j * 16 + k], cls[k], t);
        nn[j] = t;
        node[(size_t)n * 32 + j] = t;
    }

    float4 z4 = make_float4(0.f, 0.f, 0.f, 0.f);
    float4* aw = reinterpret_cast<float4*>(acc + (size_t)n * 32);
#pragma unroll
    for (int q = 0; q < 8; ++q) aw[q] = z4;

    proj_uv(nn, n, W1, u, v);
}

// ---------------- fused edge kernel: VALU L1 -> MFMA L2,L3 -> shuffle reduce -
// Barrier-free, fully wave-local. MFMA D-frag: col=lane&15 (edge within
// nt-tile), row=4*(lane>>4)+reg (channel). Segmented sum over the 16 sorted
// edges of each nt-tile via 4-step shfl_up scan; segment-end lanes issue the
// boundary atomics (adjacent lanes cover adjacent channels -> TCC merges).
#define H1STEP(j, uu, vv)                                                            \
    {                                                                                \
        float pre = fmaf(dx, W1p[(j) * 4 + 0], (uu) + (vv));                         \
        pre = fmaf(dy, W1p[(j) * 4 + 1], pre);                                       \
        pre = fmaf(dz, W1p[(j) * 4 + 2], pre);                                       \
        pre += W1p[(j) * 4 + 3];                                                     \
        h1[j] = fmaxf(pre, 0.0f);                                                    \
    }

__global__ __launch_bounds__(256, 4) void edge_kernel(
    const int2* __restrict__ sd, const float* __restrict__ pos,
    const float* __restrict__ u, const float* __restrict__ v,
    const float* __restrict__ W1p,
    const float* __restrict__ W2, const float* __restrict__ b2,
    const float* __restrict__ W3, const float* __restrict__ b3,
    float* __restrict__ acc)
{
    __shared__ unsigned stag[4][1024];    // 16KB: per-wave [kchunk][edge][8] bf16

    int tid = threadIdx.x;
    int wv = tid >> 6, lane = tid & 63;
    int l15 = lane & 15, l4 = lane >> 4;

    s8v w2f[2], w3f[2];
    f4v b2v[2], b3v[2];
#pragma unroll
    for (int mt = 0; mt < 2; ++mt) {
        const float* p2 = W2 + (mt * 16 + l15) * 32 + l4 * 8;
        const float* p3 = W3 + (mt * 16 + l15) * 32 + l4 * 8;
        float4 a0 = *(const float4*)p2;
        float4 a1 = *(const float4*)(p2 + 4);
        float4 c0 = *(const float4*)p3;
        float4 c1 = *(const float4*)(p3 + 4);
        s8v w2x, w3x;
        w2x[0] = (short)rne16(a0.x); w2x[1] = (short)rne16(a0.y);
        w2x[2] = (short)rne16(a0.z); w2x[3] = (short)rne16(a0.w);
        w2x[4] = (short)rne16(a1.x); w2x[5] = (short)rne16(a1.y);
        w2x[6] = (short)rne16(a1.z); w2x[7] = (short)rne16(a1.w);
        w3x[0] = (short)rne16(c0.x); w3x[1] = (short)rne16(c0.y);
        w3x[2] = (short)rne16(c0.z); w3x[3] = (short)rne16(c0.w);
        w3x[4] = (short)rne16(c1.x); w3x[5] = (short)rne16(c1.y);
        w3x[6] = (short)rne16(c1.z); w3x[7] = (short)rne16(c1.w);
        w2f[mt] = w2x; w3f[mt] = w3x;
        b2v[mt] = *(const f4v*)(b2 + mt * 16 + l4 * 4);
        b3v[mt] = *(const f4v*)(b3 + mt * 16 + l4 * 4);
    }

    int e = blockIdx.x * 256 + tid;           // grid exactly NE2/256
    int2 p = sd[e];
    int s = p.x, d = p.y;

    float dx = pos[d * 3 + 0] - pos[s * 3 + 0];
    float dy = pos[d * 3 + 1] - pos[s * 3 + 1];
    float dz = pos[d * 3 + 2] - pos[s * 3 + 2];

    const float4* ur = reinterpret_cast<const float4*>(u + (size_t)s * 32);
    const float4* vr = reinterpret_cast<const float4*>(v + (size_t)d * 32);

    float h1[32];
#pragma unroll
    for (int q = 0; q < 8; ++q) {
        float4 uq = ur[q];
        float4 vq = vr[q];
        H1STEP(q * 4 + 0, uq.x, vq.x);
        H1STEP(q * 4 + 1, uq.y, vq.y);
        H1STEP(q * 4 + 2, uq.z, vq.z);
        H1STEP(q * 4 + 3, uq.w, vq.w);
    }

#pragma unroll
    for (int c = 0; c < 4; ++c) {
        uint4 q;
        q.x = pkbf(h1[c * 8 + 0], h1[c * 8 + 1]);
        q.y = pkbf(h1[c * 8 + 2], h1[c * 8 + 3]);
        q.z = pkbf(h1[c * 8 + 4], h1[c * 8 + 5]);
        q.w = pkbf(h1[c * 8 + 6], h1[c * 8 + 7]);
        *(uint4*)&stag[wv][c * 256 + lane * 4] = q;
    }
    asm volatile("s_waitcnt lgkmcnt(0)" ::: "memory");
    __builtin_amdgcn_sched_barrier(0);

    s8v bf[4];
#pragma unroll
    for (int t = 0; t < 4; ++t)
        bf[t] = *(const s8v*)&stag[wv][l4 * 256 + (t * 16 + l15) * 4];

    f4v h2a[2][4];
#pragma unroll
    for (int mt = 0; mt < 2; ++mt)
#pragma unroll
        for (int t = 0; t < 4; ++t)
            h2a[mt][t] = __builtin_amdgcn_mfma_f32_16x16x32_bf16(
                w2f[mt], bf[t], b2v[mt], 0, 0, 0);

#pragma unroll
    for (int mt = 0; mt < 2; ++mt) {
        int kc = mt * 2 + (l4 >> 1);
#pragma unroll
        for (int t = 0; t < 4; ++t) {
            float e0 = fmaxf(h2a[mt][t][0], 0.0f);
            float e1 = fmaxf(h2a[mt][t][1], 0.0f);
            float e2 = fmaxf(h2a[mt][t][2], 0.0f);
            float e3 = fmaxf(h2a[mt][t][3], 0.0f);
            uint2 w; w.x = pkbf(e0, e1); w.y = pkbf(e2, e3);
            *(uint2*)&stag[wv][kc * 256 + (t * 16 + l15) * 4 + (l4 & 1) * 2] = w;
        }
    }
    asm volatile("s_waitcnt lgkmcnt(0)" ::: "memory");
    __builtin_amdgcn_sched_barrier(0);

#pragma unroll
    for (int t = 0; t < 4; ++t)
        bf[t] = *(const s8v*)&stag[wv][l4 * 256 + (t * 16 + l15) * 4];

    f4v ma[2][4];
#pragma unroll
    for (int mt = 0; mt < 2; ++mt)
#pragma unroll
        for (int t = 0; t < 4; ++t)
            ma[mt][t] = __builtin_amdgcn_mfma_f32_16x16x32_bf16(
                w3f[mt], bf[t], b3v[mt], 0, 0, 0);

    // ---- in-register segmented reduce over each nt-tile's 16 sorted edges ----
#pragma unroll
    for (int nt = 0; nt < 4; ++nt) {
        int st = __shfl(s, nt * 16 + l15);     // source id of this frag's edge
        f4v m0 = ma[0][nt], m1 = ma[1][nt];
#pragma unroll
        for (int k = 1; k < 16; k <<= 1) {     // Hillis-Steele segmented scan
            int sk = __shfl_up(st, k, 16);
            f4v t0, t1;
#pragma unroll
            for (int r = 0; r < 4; ++r) {
                t0[r] = __shfl_up(m0[r], k, 16);
                t1[r] = __shfl_up(m1[r], k, 16);
            }
            bool addf = (l15 >= k) && (sk == st);   // sorted: equal-at-k => run
#pragma unroll
            for (int r = 0; r < 4; ++r) {
                m0[r] += addf ? t0[r] : 0.0f;
                m1[r] += addf ? t1[r] : 0.0f;
            }
        }
        int sn = __shfl_down(st, 1, 16);
        if ((l15 == 15) || (sn != st)) {       // segment-end lane
            float* row = acc + (size_t)st * 32 + 4 * l4;
#pragma unroll
            for (int r = 0; r < 4; ++r) {
                unsafeAtomicAdd(row + r,      m0[r]);
                unsafeAtomicAdd(row + 16 + r, m1[r]);
            }
        }
    }
}

// ---------------- MFMA node kernel: 1 wave / 64 nodes, grid 782 --------------
__global__ __launch_bounds__(64) void node_mfma_kernel(
    float* __restrict__ node, float* __restrict__ acc,
    const u16* __restrict__ Wg_bf, const float* __restrict__ bg,
    const u16* __restrict__ Wp_bf,
    float* __restrict__ u, float* __restrict__ v, int last)
{
    __shared__ short stag[8][64][8];   // 8KB bf16 [kchunk][node][8k]
    __shared__ float hlds[64][36];     // 9.2KB f32 h rows -> out rows

    int lane = threadIdx.x;            // 0..63
    int l15 = lane & 15, l4 = lane >> 4;
    int base = blockIdx.x * 64;
    int xg = base + lane;              // this lane's staging node
    bool xv = xg < NN;

    float a[32], h[32];
    if (xv) {
        const f4v* ar = (const f4v*)(acc + (size_t)xg * 32);
        const f4v* hr = (const f4v*)(node + (size_t)xg * 32);
#pragma unroll
        for (int q = 0; q < 8; ++q) {
            f4v t4 = ar[q];
            a[q*4+0] = t4[0]; a[q*4+1] = t4[1]; a[q*4+2] = t4[2]; a[q*4+3] = t4[3];
            f4v s4 = hr[q];
            h[q*4+0] = s4[0]; h[q*4+1] = s4[1]; h[q*4+2] = s4[2]; h[q*4+3] = s4[3];
        }
        f4v z4 = {0.f, 0.f, 0.f, 0.f};
        f4v* aw = (f4v*)(acc + (size_t)xg * 32);
#pragma unroll
        for (int q = 0; q < 8; ++q) aw[q] = z4;
    } else {
#pragma unroll
        for (int q = 0; q < 32; ++q) { a[q] = 0.0f; h[q] = 0.0f; }
    }
#pragma unroll
    for (int kc = 0; kc < 4; ++kc) {
        *(s8v*)&stag[kc][lane][0]     = pack8(&a[kc * 8]);
        *(s8v*)&stag[4 + kc][lane][0] = pack8(&h[kc * 8]);
    }
#pragma unroll
    for (int q = 0; q < 8; ++q) {
        f4v hv = {h[q*4+0], h[q*4+1], h[q*4+2], h[q*4+3]};
        *(f4v*)&hlds[lane][q * 4] = hv;
    }
    asm volatile("s_waitcnt lgkmcnt(0)" ::: "memory");
    __builtin_amdgcn_sched_barrier(0);

    s8v wa0[8], wa1[8];
    f4v bias[8];
#pragma unroll
    for (int mt = 0; mt < 8; ++mt) {
        int row = mt * 16 + l15;
        wa0[mt]  = *(const s8v*)(Wg_bf + row * 64 + l4 * 8);
        wa1[mt]  = *(const s8v*)(Wg_bf + row * 64 + 32 + l4 * 8);
        bias[mt] = *(const f4v*)(bg + mt * 16 + l4 * 4);
    }

#pragma unroll
    for (int nt = 0; nt < 4; ++nt) {
        s8v b0 = *(const s8v*)&stag[l4][nt * 16 + l15][0];      // a chunk
        s8v b1 = *(const s8v*)&stag[4 + l4][nt * 16 + l15][0];  // h chunk
        f4v g[8];
#pragma unroll
        for (int mt = 0; mt < 8; ++mt) {
            f4v cacc = __builtin_amdgcn_mfma_f32_16x16x32_bf16(wa0[mt], b0,
                                                               bias[mt], 0, 0, 0);
            g[mt] = __builtin_amdgcn_mfma_f32_16x16x32_bf16(wa1[mt], b1,
                                                            cacc, 0, 0, 0);
        }
        int nd = nt * 16 + l15;
        f4v hv0 = *(f4v*)&hlds[nd][4 * l4];        // h[j], j=4l4+r
        f4v hv1 = *(f4v*)&hlds[nd][16 + 4 * l4];   // h[j], j=16+4l4+r
        f4v o0, o1;
#pragma unroll
        for (int r = 0; r < 4; ++r) {
            o0[r] = gru1(g[0][r], g[2][r], g[4][r], g[6][r], hv0[r]);
            o1[r] = gru1(g[1][r], g[3][r], g[5][r], g[7][r], hv1[r]);
        }
        *(f4v*)&hlds[nd][4 * l4] = o0;             // same lane/addrs as read
        *(f4v*)&hlds[nd][16 + 4 * l4] = o1;
    }
    asm volatile("s_waitcnt lgkmcnt(0)" ::: "memory");
    __builtin_amdgcn_sched_barrier(0);

    float nn[32];
#pragma unroll
    for (int q = 0; q < 8; ++q) {
        f4v t4 = *(f4v*)&hlds[lane][q * 4];
        nn[q*4+0] = t4[0]; nn[q*4+1] = t4[1]; nn[q*4+2] = t4[2]; nn[q*4+3] = t4[3];
    }
    if (xv) {
        f4v* nw = (f4v*)(node + (size_t)xg * 32);
#pragma unroll
        for (int q = 0; q < 8; ++q) {
            f4v t4 = {nn[q*4+0], nn[q*4+1], nn[q*4+2], nn[q*4+3]};
            nw[q] = t4;
        }
    }
    if (last) return;

#pragma unroll
    for (int kc = 0; kc < 4; ++kc)
        *(s8v*)&stag[kc][lane][0] = pack8(&nn[kc * 8]);
    asm volatile("s_waitcnt lgkmcnt(0)" ::: "memory");
    __builtin_amdgcn_sched_barrier(0);

#pragma unroll
    for (int nt = 0; nt < 4; ++nt) {
        s8v b = *(const s8v*)&stag[l4][nt * 16 + l15][0];
        int nd = base + nt * 16 + l15;
        bool nv = nd < NN;
#pragma unroll
        for (int mt = 0; mt < 4; ++mt) {
            s8v aa = *(const s8v*)(Wp_bf + (mt * 16 + l15) * 32 + l4 * 8);
            f4v cz = {0.f, 0.f, 0.f, 0.f};
            f4v pr = __builtin_amdgcn_mfma_f32_16x16x32_bf16(aa, b, cz, 0, 0, 0);
            if (nv) {
                float* dst = (mt < 2)
                    ? (u + (size_t)nd * 32 + mt * 16 + 4 * l4)
                    : (v + (size_t)nd * 32 + (mt - 2) * 16 + 4 * l4);
                *(f4v*)dst = pr;
            }
        }
    }
}

// ---------------- launch ----------------
extern "C" void kernel_launch(void* const* d_in, const int* in_sizes, int n_in,
                              void* d_out, int out_size, void* d_ws, size_t ws_size,
                              hipStream_t stream)
{
    const float* pos     = (const float*)d_in[0];
    const float* classes = (const float*)d_in[1];
    const int*   edges   = (const int*)d_in[2];
    const float* W_in = (const float*)d_in[4];
    const float* b_in = (const float*)d_in[5];
    const float* W1   = (const float*)d_in[6];
    const float* b1   = (const float*)d_in[7];
    const float* W2   = (const float*)d_in[8];
    const float* b2   = (const float*)d_in[9];
    const float* W3   = (const float*)d_in[10];
    const float* b3   = (const float*)d_in[11];
    const float* Wih_n = (const float*)d_in[12];
    const float* Whh_n = (const float*)d_in[13];
    const float* bih_n = (const float*)d_in[14];
    const float* bhh_n = (const float*)d_in[15];
    // d_in[16..19]: edge-GRU params — dead w.r.t. the output.

    float* node = (float*)d_out;                  // [NN][32] persistent

    float* ws  = (float*)d_ws;
    float* u   = ws;                              // [NN][32]
    float* v   = u + (size_t)NN * 32;             // [NN][32]
    float* acc = v + (size_t)NN * 32;             // [NN][32]
    float* bg  = acc + (size_t)NN * 32;           // [128]
    float* W1p = bg + 128;                        // [128]
    u16* Wg_bf = (u16*)(W1p + 128);               // [128][64] bf16 (16B-aligned)
    u16* Wp_bf = Wg_bf + 8192;                    // [64][32] bf16
    int* bsum   = (int*)(Wp_bf + 2048);           // [256]
    int* boff   = bsum + 256;                     // [256]
    int* deg    = boff + 256;                     // [NN]
    int* rank   = deg + NN;                       // [NE2]
    int* rowptr = rank + NE2;                     // [NN+1]
    uintptr_t sp = (uintptr_t)(rowptr + NN + 1);
    sp = (sp + 255) & ~(uintptr_t)255;
    int2* sd = (int2*)sp;                         // [NE2] packed (s,d)

    const int* e0 = edges;
    const int* e1 = edges + NE;

    prep_kernel<<<41, 256, 0, stream>>>(Wih_n, Whh_n, bih_n, bhh_n, W1, b1,
                                        Wg_bf, bg, W1p, Wp_bf);
    hipMemsetAsync(deg, 0, (size_t)NN * sizeof(int), stream);
    hist_rank_kernel<<<NE2 / 256, 256, 0, stream>>>(e0, e1, deg, rank);
    scan_part_kernel<<<NBLK, 256, 0, stream>>>(deg, bsum);
    scan_mid_kernel<<<1, 256, 0, stream>>>(bsum, boff, rowptr);
    scan_apply_kernel<<<NBLK, 256, 0, stream>>>(deg, boff, rowptr);
    scatter_kernel<<<NE2 / 256, 256, 0, stream>>>(e0, e1, rowptr, rank, sd);
    init_kernel<<<NBLK, 256, 0, stream>>>(classes, W_in, b_in, W1,
                                          node, u, v, acc);
    for (int it = 0; it < 6; ++it) {
        edge_kernel<<<NE2 / 256, 256, 0, stream>>>(sd, pos, u, v, W1p,
                                                   W2, b2, W3, b3, acc);
        node_mfma_kernel<<<(NN + 63) / 64, 64, 0, stream>>>(node, acc, Wg_bf, bg,
                                                            Wp_bf, u, v, it == 5);
    }
}

// Round 13
// 763.359 us; speedup vs baseline: 1.1526x; 1.1526x over previous
//
#include <hip/hip_runtime.h>

// MPNN encoder, MI355X — round 13.
// Round-12 regression diagnosed: shuffle-scan reduce scattered its boundary
// atomics (4B per lane, 32 ops per 128B row) -> WRITE 21.5->73.4MB (3.4x
// amplification) + 128 ds_bpermute/wave. REVERT edge to round-10 structure
// (union LDS, 2-phase coalesced reduce: 32 consecutive lanes -> 32 consecutive
// channels, TCC-merged). NEW: all 4 edge barriers order LDS only -> replace
// __syncthreads() (which drains vmcnt=atomics, ~900cy) with raw
// s_waitcnt lgkmcnt(0) + s_barrier; atomics stay in flight across barriers.
//
//  - edge_feat / GRU_e dead w.r.t. output -> skipped.
//  - layer1 factorized: h1 = relu(u[s] + v[d] + dpos.W1p + b1).
//  - edge L2,L3 + node GRU/proj on MFMA (bf16 operands, f32 accum).

#define NN      50000
#define NE      800000
#define NE2     (2 * NE)
#define NCLS    16
#define NBLK    196                               // ceil(NN/256)

typedef short s8v __attribute__((ext_vector_type(8)));   // 8 bf16 (4 VGPRs)
typedef float f4v __attribute__((ext_vector_type(4)));   // MFMA C/D
typedef unsigned short u16;

__device__ __forceinline__ unsigned rne16(float f) {     // f32 -> bf16 bits (RNE)
    unsigned u = __float_as_uint(f);
    return (u + 0x7FFFu + ((u >> 16) & 1u)) >> 16;
}
__device__ __forceinline__ unsigned pkbf(float lo, float hi) {
    return rne16(lo) | (rne16(hi) << 16);
}
__device__ __forceinline__ s8v pack8(const float* f) {
    s8v r;
#pragma unroll
    for (int i = 0; i < 8; ++i) r[i] = (short)rne16(f[i]);
    return r;
}
__device__ __forceinline__ float gru1(float gr, float gz, float gin, float ghn,
                                      float h) {
    float r  = __builtin_amdgcn_rcpf(1.0f + __expf(-gr));
    float z  = __builtin_amdgcn_rcpf(1.0f + __expf(-gz));
    float pre = fmaf(r, ghn, gin);
    float nj = 1.0f - 2.0f * __builtin_amdgcn_rcpf(1.0f + __expf(2.0f * pre));
    return fmaf(z, h - nj, nj);                   // (1-z)*n + z*h
}

// LDS-only barrier: wait local ops, fence the scheduler, raw s_barrier —
// does NOT drain vmcnt, so in-flight atomics cross it freely.
__device__ __forceinline__ void lds_barrier() {
    asm volatile("s_waitcnt lgkmcnt(0)" ::: "memory");
    __builtin_amdgcn_sched_barrier(0);
    __builtin_amdgcn_s_barrier();
    __builtin_amdgcn_sched_barrier(0);
}

// ---------------- prep: bg, W1p, bf16 Wg and bf16 proj weights ----------------
__global__ __launch_bounds__(256) void prep_kernel(
    const float* __restrict__ Wih, const float* __restrict__ Whh,
    const float* __restrict__ bih, const float* __restrict__ bhh,
    const float* __restrict__ W1, const float* __restrict__ b1,
    u16* __restrict__ Wg_bf, float* __restrict__ bg, float* __restrict__ W1p,
    u16* __restrict__ Wp_bf)
{
    int idx = blockIdx.x * 256 + threadIdx.x;
    if (idx < 8192) {
        int o = idx >> 6, k = idx & 63;
        float val;
        if (o < 64) {
            val = (k < 32) ? Wih[o * 32 + k] : Whh[o * 32 + (k - 32)];
        } else if (o < 96) {
            val = (k < 32) ? Wih[o * 32 + k] : 0.0f;
        } else {
            val = (k >= 32) ? Whh[(o - 32) * 32 + (k - 32)] : 0.0f;
        }
        Wg_bf[idx] = (u16)rne16(val);
    } else if (idx < 8320) {
        int i = idx - 8192;
        float val;
        if (i < 64)       val = bih[i] + bhh[i];
        else if (i < 96)  val = bih[i];
        else              val = bhh[i - 32];
        bg[i] = val;
    } else if (idx < 8448) {
        int t = idx - 8320;                    // W1p[j][c]: wx,wy,wz,b1
        int j = t >> 2, c = t & 3;
        W1p[t] = (c < 3) ? W1[j * 67 + 64 + c] : b1[j];
    } else if (idx < 10496) {
        int t = idx - 8448;                    // Wp_bf[r][k]
        int r = t >> 5, k = t & 31;
        float val = (r < 32) ? W1[r * 67 + k] : W1[(r - 32) * 67 + 32 + k];
        Wp_bf[t] = (u16)rne16(val);
    }
}

// ---------------- sort: rank-histogram, 3-kernel scan, scatter ----------------
__global__ __launch_bounds__(256) void hist_rank_kernel(
    const int* __restrict__ e0, const int* __restrict__ e1,
    int* __restrict__ deg, int* __restrict__ rank)
{
    int e = blockIdx.x * 256 + threadIdx.x;   // grid exactly NE2/256
    int s = (e < NE) ? e0[e] : e1[e - NE];
    rank[e] = atomicAdd(&deg[s], 1);          // rank store is coalesced
}

__global__ __launch_bounds__(256) void scan_part_kernel(
    const int* __restrict__ deg, int* __restrict__ bsum)
{
    int t = blockIdx.x * 256 + threadIdx.x;
    int x = (t < NN) ? deg[t] : 0;
#pragma unroll
    for (int off = 1; off < 64; off <<= 1) x += __shfl_xor(x, off);
    __shared__ int wsum[4];
    if ((threadIdx.x & 63) == 0) wsum[threadIdx.x >> 6] = x;
    __syncthreads();
    if (threadIdx.x == 0)
        bsum[blockIdx.x] = wsum[0] + wsum[1] + wsum[2] + wsum[3];
}

__global__ __launch_bounds__(256) void scan_mid_kernel(
    const int* __restrict__ bsum, int* __restrict__ boff, int* __restrict__ rowptr)
{
    __shared__ int sd[256];
    int t = threadIdx.x;
    int x = (t < NBLK) ? bsum[t] : 0;
    sd[t] = x;
    __syncthreads();
    for (int off = 1; off < 256; off <<= 1) {
        int vv = (t >= off) ? sd[t - off] : 0;
        __syncthreads();
        sd[t] += vv;
        __syncthreads();
    }
    if (t < NBLK) boff[t] = sd[t] - x;         // exclusive block offsets
    if (t == 0) rowptr[NN] = NE2;              // total degree is constant
}

__global__ __launch_bounds__(256) void scan_apply_kernel(
    const int* __restrict__ deg, const int* __restrict__ boff,
    int* __restrict__ rowptr)
{
    __shared__ int sd[256];
    int tid = threadIdx.x;
    int t = blockIdx.x * 256 + tid;
    int x = (t < NN) ? deg[t] : 0;
    sd[tid] = x;
    __syncthreads();
    for (int off = 1; off < 256; off <<= 1) {
        int vv = (tid >= off) ? sd[tid - off] : 0;
        __syncthreads();
        sd[tid] += vv;
        __syncthreads();
    }
    if (t < NN) rowptr[t] = boff[blockIdx.x] + sd[tid] - x;   // exclusive
}

__global__ __launch_bounds__(256) void scatter_kernel(
    const int* __restrict__ e0, const int* __restrict__ e1,
    const int* __restrict__ rowptr, const int* __restrict__ rank,
    int2* __restrict__ sd)
{
    int e = blockIdx.x * 256 + threadIdx.x;   // grid exactly NE2/256
    int s, d;
    if (e < NE) { s = e0[e]; d = e1[e]; }
    else        { s = e1[e - NE]; d = e0[e - NE]; }
    int p = rowptr[s] + rank[e];
    sd[p] = make_int2(s, d);                  // single scattered 8B store
}

// ---------------- u,v projection (init only, f32) ----------------
__device__ __forceinline__ void proj_uv(const float nn[32], int n,
                                        const float* __restrict__ W1,
                                        float* __restrict__ u, float* __restrict__ v)
{
    for (int j = 0; j < 32; ++j) {            // rolled: W1 addrs uniform -> s_load
        float su = 0.0f, sv = 0.0f;
#pragma unroll
        for (int k = 0; k < 32; ++k) {
            su = fmaf(W1[j * 67 + k],      nn[k], su);
            sv = fmaf(W1[j * 67 + 32 + k], nn[k], sv);
        }
        u[(size_t)n * 32 + j] = su;
        v[(size_t)n * 32 + j] = sv;
    }
}

// ---------------- init: node = classes@W_in.T + b_in; emit u,v; zero acc ------
__global__ __launch_bounds__(256) void init_kernel(
    const float* __restrict__ classes, const float* __restrict__ W_in,
    const float* __restrict__ b_in, const float* __restrict__ W1,
    float* __restrict__ node, float* __restrict__ u, float* __restrict__ v,
    float* __restrict__ acc)
{
    int n = blockIdx.x * 256 + threadIdx.x;
    if (n >= NN) return;

    float cls[16];
    const float4* cr = reinterpret_cast<const float4*>(classes + (size_t)n * NCLS);
#pragma unroll
    for (int q = 0; q < 4; ++q) {
        float4 c4 = cr[q];
        cls[q * 4 + 0] = c4.x; cls[q * 4 + 1] = c4.y;
        cls[q * 4 + 2] = c4.z; cls[q * 4 + 3] = c4.w;
    }

    float nn[32];
#pragma unroll
    for (int j = 0; j < 32; ++j) {
        float t = b_in[j];
#pragma unroll
        for (int k = 0; k < 16; ++k) t = fmaf(W_in[j * 16 + k], cls[k], t);
        nn[j] = t;
        node[(size_t)n * 32 + j] = t;
    }

    float4 z4 = make_float4(0.f, 0.f, 0.f, 0.f);
    float4* aw = reinterpret_cast<float4*>(acc + (size_t)n * 32);
#pragma unroll
    for (int q = 0; q < 8; ++q) aw[q] = z4;

    proj_uv(nn, n, W1, u, v);
}

// ---------------- fused edge kernel: VALU L1 -> MFMA L2,L3 -> 2-phase reduce -
// r10 structure (union LDS 19.4KB) with LDS-only barriers (no vmcnt drain).
#define H1STEP(j, uu, vv)                                                            \
    {                                                                                \
        float pre = fmaf(dx, W1p[(j) * 4 + 0], (uu) + (vv));                         \
        pre = fmaf(dy, W1p[(j) * 4 + 1], pre);                                       \
        pre = fmaf(dz, W1p[(j) * 4 + 2], pre);                                       \
        pre += W1p[(j) * 4 + 3];                                                     \
        h1[j] = fmaxf(pre, 0.0f);                                                    \
    }

__global__ __launch_bounds__(256, 4) void edge_kernel(
    const int2* __restrict__ sd, const float* __restrict__ pos,
    const float* __restrict__ u, const float* __restrict__ v,
    const float* __restrict__ W1p,
    const float* __restrict__ W2, const float* __restrict__ b2,
    const float* __restrict__ W3, const float* __restrict__ b3,
    float* __restrict__ acc)
{
    __shared__ int slds[256];                        // 1KB (full lifetime)
    __shared__ __align__(16) char uni[18432];        // union: stag 16K / mld 18K
    unsigned (*stag)[1024] = (unsigned (*)[1024])uni;  // [4][1024] per-wave
    float (*mld)[36] = (float (*)[36])uni;             // [128][36]

    int tid = threadIdx.x;
    int wv = tid >> 6, lane = tid & 63;
    int l15 = lane & 15, l4 = lane >> 4;

    s8v w2f[2], w3f[2];
    f4v b2v[2], b3v[2];
#pragma unroll
    for (int mt = 0; mt < 2; ++mt) {
        const float* p2 = W2 + (mt * 16 + l15) * 32 + l4 * 8;
        const float* p3 = W3 + (mt * 16 + l15) * 32 + l4 * 8;
        float4 a0 = *(const float4*)p2;
        float4 a1 = *(const float4*)(p2 + 4);
        float4 c0 = *(const float4*)p3;
        float4 c1 = *(const float4*)(p3 + 4);
        s8v w2x, w3x;
        w2x[0] = (short)rne16(a0.x); w2x[1] = (short)rne16(a0.y);
        w2x[2] = (short)rne16(a0.z); w2x[3] = (short)rne16(a0.w);
        w2x[4] = (short)rne16(a1.x); w2x[5] = (short)rne16(a1.y);
        w2x[6] = (short)rne16(a1.z); w2x[7] = (short)rne16(a1.w);
        w3x[0] = (short)rne16(c0.x); w3x[1] = (short)rne16(c0.y);
        w3x[2] = (short)rne16(c0.z); w3x[3] = (short)rne16(c0.w);
        w3x[4] = (short)rne16(c1.x); w3x[5] = (short)rne16(c1.y);
        w3x[6] = (short)rne16(c1.z); w3x[7] = (short)rne16(c1.w);
        w2f[mt] = w2x; w3f[mt] = w3x;
        b2v[mt] = *(const f4v*)(b2 + mt * 16 + l4 * 4);
        b3v[mt] = *(const f4v*)(b3 + mt * 16 + l4 * 4);
    }

    int e = blockIdx.x * 256 + tid;           // grid exactly NE2/256
    int2 p = sd[e];
    int s = p.x, d = p.y;
    slds[tid] = s;

    float dx = pos[d * 3 + 0] - pos[s * 3 + 0];
    float dy = pos[d * 3 + 1] - pos[s * 3 + 1];
    float dz = pos[d * 3 + 2] - pos[s * 3 + 2];

    const float4* ur = reinterpret_cast<const float4*>(u + (size_t)s * 32);
    const float4* vr = reinterpret_cast<const float4*>(v + (size_t)d * 32);

    float h1[32];
#pragma unroll
    for (int q = 0; q < 8; ++q) {
        float4 uq = ur[q];
        float4 vq = vr[q];
        H1STEP(q * 4 + 0, uq.x, vq.x);
        H1STEP(q * 4 + 1, uq.y, vq.y);
        H1STEP(q * 4 + 2, uq.z, vq.z);
        H1STEP(q * 4 + 3, uq.w, vq.w);
    }

#pragma unroll
    for (int c = 0; c < 4; ++c) {
        uint4 q;
        q.x = pkbf(h1[c * 8 + 0], h1[c * 8 + 1]);
        q.y = pkbf(h1[c * 8 + 2], h1[c * 8 + 3]);
        q.z = pkbf(h1[c * 8 + 4], h1[c * 8 + 5]);
        q.w = pkbf(h1[c * 8 + 6], h1[c * 8 + 7]);
        *(uint4*)&stag[wv][c * 256 + lane * 4] = q;
    }
    asm volatile("s_waitcnt lgkmcnt(0)" ::: "memory");   // wave-internal RAW
    __builtin_amdgcn_sched_barrier(0);

    s8v bf[4];
#pragma unroll
    for (int t = 0; t < 4; ++t)
        bf[t] = *(const s8v*)&stag[wv][l4 * 256 + (t * 16 + l15) * 4];

    f4v h2a[2][4];
#pragma unroll
    for (int mt = 0; mt < 2; ++mt)
#pragma unroll
        for (int t = 0; t < 4; ++t)
            h2a[mt][t] = __builtin_amdgcn_mfma_f32_16x16x32_bf16(
                w2f[mt], bf[t], b2v[mt], 0, 0, 0);

#pragma unroll
    for (int mt = 0; mt < 2; ++mt) {
        int kc = mt * 2 + (l4 >> 1);
#pragma unroll
        for (int t = 0; t < 4; ++t) {
            float e0 = fmaxf(h2a[mt][t][0], 0.0f);
            float e1 = fmaxf(h2a[mt][t][1], 0.0f);
            float e2 = fmaxf(h2a[mt][t][2], 0.0f);
            float e3 = fmaxf(h2a[mt][t][3], 0.0f);
            uint2 w; w.x = pkbf(e0, e1); w.y = pkbf(e2, e3);
            *(uint2*)&stag[wv][kc * 256 + (t * 16 + l15) * 4 + (l4 & 1) * 2] = w;
        }
    }
    asm volatile("s_waitcnt lgkmcnt(0)" ::: "memory");   // wave-internal RAW
    __builtin_amdgcn_sched_barrier(0);

#pragma unroll
    for (int t = 0; t < 4; ++t)
        bf[t] = *(const s8v*)&stag[wv][l4 * 256 + (t * 16 + l15) * 4];
    lds_barrier();                                       // uni becomes mld

    f4v ma[2][4];
#pragma unroll
    for (int mt = 0; mt < 2; ++mt)
#pragma unroll
        for (int t = 0; t < 4; ++t)
            ma[mt][t] = __builtin_amdgcn_mfma_f32_16x16x32_bf16(
                w3f[mt], bf[t], b3v[mt], 0, 0, 0);

    int c = tid & 31, g = tid >> 5;            // 32 cols x 8 row-groups

    if (wv < 2) {                              // phase-1 rows: 0..127
#pragma unroll
        for (int mt = 0; mt < 2; ++mt)
#pragma unroll
            for (int t = 0; t < 4; ++t)
                *(f4v*)&mld[wv * 64 + t * 16 + l15][mt * 16 + l4 * 4] = ma[mt][t];
    }
    lds_barrier();
    {
        int base = g * 16;
        int scur = slds[base];
        float sum = 0.0f;
        for (int r = 0; r < 16; ++r) {
            int row = base + r;
            int sr = slds[row];
            if (sr != scur) {
                unsafeAtomicAdd(&acc[(size_t)scur * 32 + c], sum);
                sum = 0.0f;
                scur = sr;
            }
            sum += mld[row][c];
        }
        unsafeAtomicAdd(&acc[(size_t)scur * 32 + c], sum);
    }
    lds_barrier();                             // atomics stay in flight

    if (wv >= 2) {                             // phase-2 rows: 128..255
#pragma unroll
        for (int mt = 0; mt < 2; ++mt)
#pragma unroll
            for (int t = 0; t < 4; ++t)
                *(f4v*)&mld[(wv - 2) * 64 + t * 16 + l15][mt * 16 + l4 * 4] = ma[mt][t];
    }
    lds_barrier();
    {
        int base = 128 + g * 16;
        int scur = slds[base];
        float sum = 0.0f;
        for (int r = 0; r < 16; ++r) {
            int row = base + r;
            int sr = slds[row];
            if (sr != scur) {
                unsafeAtomicAdd(&acc[(size_t)scur * 32 + c], sum);
                sum = 0.0f;
                scur = sr;
            }
            sum += mld[row - 128][c];
        }
        unsafeAtomicAdd(&acc[(size_t)scur * 32 + c], sum);
    }
}

// ---------------- MFMA node kernel: 1 wave / 64 nodes, grid 782 --------------
__global__ __launch_bounds__(64) void node_mfma_kernel(
    float* __restrict__ node, float* __restrict__ acc,
    const u16* __restrict__ Wg_bf, const float* __restrict__ bg,
    const u16* __restrict__ Wp_bf,
    float* __restrict__ u, float* __restrict__ v, int last)
{
    __shared__ short stag[8][64][8];   // 8KB bf16 [kchunk][node][8k]
    __shared__ float hlds[64][36];     // 9.2KB f32 h rows -> out rows

    int lane = threadIdx.x;            // 0..63
    int l15 = lane & 15, l4 = lane >> 4;
    int base = blockIdx.x * 64;
    int xg = base + lane;              // this lane's staging node
    bool xv = xg < NN;

    float a[32], h[32];
    if (xv) {
        const f4v* ar = (const f4v*)(acc + (size_t)xg * 32);
        const f4v* hr = (const f4v*)(node + (size_t)xg * 32);
#pragma unroll
        for (int q = 0; q < 8; ++q) {
            f4v t4 = ar[q];
            a[q*4+0] = t4[0]; a[q*4+1] = t4[1]; a[q*4+2] = t4[2]; a[q*4+3] = t4[3];
            f4v s4 = hr[q];
            h[q*4+0] = s4[0]; h[q*4+1] = s4[1]; h[q*4+2] = s4[2]; h[q*4+3] = s4[3];
        }
        f4v z4 = {0.f, 0.f, 0.f, 0.f};
        f4v* aw = (f4v*)(acc + (size_t)xg * 32);
#pragma unroll
        for (int q = 0; q < 8; ++q) aw[q] = z4;
    } else {
#pragma unroll
        for (int q = 0; q < 32; ++q) { a[q] = 0.0f; h[q] = 0.0f; }
    }
#pragma unroll
    for (int kc = 0; kc < 4; ++kc) {
        *(s8v*)&stag[kc][lane][0]     = pack8(&a[kc * 8]);
        *(s8v*)&stag[4 + kc][lane][0] = pack8(&h[kc * 8]);
    }
#pragma unroll
    for (int q = 0; q < 8; ++q) {
        f4v hv = {h[q*4+0], h[q*4+1], h[q*4+2], h[q*4+3]};
        *(f4v*)&hlds[lane][q * 4] = hv;
    }
    asm volatile("s_waitcnt lgkmcnt(0)" ::: "memory");
    __builtin_amdgcn_sched_barrier(0);

    s8v wa0[8], wa1[8];
    f4v bias[8];
#pragma unroll
    for (int mt = 0; mt < 8; ++mt) {
        int row = mt * 16 + l15;
        wa0[mt]  = *(const s8v*)(Wg_bf + row * 64 + l4 * 8);
        wa1[mt]  = *(const s8v*)(Wg_bf + row * 64 + 32 + l4 * 8);
        bias[mt] = *(const f4v*)(bg + mt * 16 + l4 * 4);
    }

#pragma unroll
    for (int nt = 0; nt < 4; ++nt) {
        s8v b0 = *(const s8v*)&stag[l4][nt * 16 + l15][0];      // a chunk
        s8v b1 = *(const s8v*)&stag[4 + l4][nt * 16 + l15][0];  // h chunk
        f4v g[8];
#pragma unroll
        for (int mt = 0; mt < 8; ++mt) {
            f4v cacc = __builtin_amdgcn_mfma_f32_16x16x32_bf16(wa0[mt], b0,
                                                               bias[mt], 0, 0, 0);
            g[mt] = __builtin_amdgcn_mfma_f32_16x16x32_bf16(wa1[mt], b1,
                                                            cacc, 0, 0, 0);
        }
        int nd = nt * 16 + l15;
        f4v hv0 = *(f4v*)&hlds[nd][4 * l4];        // h[j], j=4l4+r
        f4v hv1 = *(f4v*)&hlds[nd][16 + 4 * l4];   // h[j], j=16+4l4+r
        f4v o0, o1;
#pragma unroll
        for (int r = 0; r < 4; ++r) {
            o0[r] = gru1(g[0][r], g[2][r], g[4][r], g[6][r], hv0[r]);
            o1[r] = gru1(g[1][r], g[3][r], g[5][r], g[7][r], hv1[r]);
        }
        *(f4v*)&hlds[nd][4 * l4] = o0;             // same lane/addrs as read
        *(f4v*)&hlds[nd][16 + 4 * l4] = o1;
    }
    asm volatile("s_waitcnt lgkmcnt(0)" ::: "memory");
    __builtin_amdgcn_sched_barrier(0);

    float nn[32];
#pragma unroll
    for (int q = 0; q < 8; ++q) {
        f4v t4 = *(f4v*)&hlds[lane][q * 4];
        nn[q*4+0] = t4[0]; nn[q*4+1] = t4[1]; nn[q*4+2] = t4[2]; nn[q*4+3] = t4[3];
    }
    if (xv) {
        f4v* nw = (f4v*)(node + (size_t)xg * 32);
#pragma unroll
        for (int q = 0; q < 8; ++q) {
            f4v t4 = {nn[q*4+0], nn[q*4+1], nn[q*4+2], nn[q*4+3]};
            nw[q] = t4;
        }
    }
    if (last) return;

#pragma unroll
    for (int kc = 0; kc < 4; ++kc)
        *(s8v*)&stag[kc][lane][0] = pack8(&nn[kc * 8]);
    asm volatile("s_waitcnt lgkmcnt(0)" ::: "memory");
    __builtin_amdgcn_sched_barrier(0);

#pragma unroll
    for (int nt = 0; nt < 4; ++nt) {
        s8v b = *(const s8v*)&stag[l4][nt * 16 + l15][0];
        int nd = base + nt * 16 + l15;
        bool nv = nd < NN;
#pragma unroll
        for (int mt = 0; mt < 4; ++mt) {
            s8v aa = *(const s8v*)(Wp_bf + (mt * 16 + l15) * 32 + l4 * 8);
            f4v cz = {0.f, 0.f, 0.f, 0.f};
            f4v pr = __builtin_amdgcn_mfma_f32_16x16x32_bf16(aa, b, cz, 0, 0, 0);
            if (nv) {
                float* dst = (mt < 2)
                    ? (u + (size_t)nd * 32 + mt * 16 + 4 * l4)
                    : (v + (size_t)nd * 32 + (mt - 2) * 16 + 4 * l4);
                *(f4v*)dst = pr;
            }
        }
    }
}

// ---------------- launch ----------------
extern "C" void kernel_launch(void* const* d_in, const int* in_sizes, int n_in,
                              void* d_out, int out_size, void* d_ws, size_t ws_size,
                              hipStream_t stream)
{
    const float* pos     = (const float*)d_in[0];
    const float* classes = (const float*)d_in[1];
    const int*   edges   = (const int*)d_in[2];
    const float* W_in = (const float*)d_in[4];
    const float* b_in = (const float*)d_in[5];
    const float* W1   = (const float*)d_in[6];
    const float* b1   = (const float*)d_in[7];
    const float* W2   = (const float*)d_in[8];
    const float* b2   = (const float*)d_in[9];
    const float* W3   = (const float*)d_in[10];
    const float* b3   = (const float*)d_in[11];
    const float* Wih_n = (const float*)d_in[12];
    const float* Whh_n = (const float*)d_in[13];
    const float* bih_n = (const float*)d_in[14];
    const float* bhh_n = (const float*)d_in[15];
    // d_in[16..19]: edge-GRU params — dead w.r.t. the output.

    float* node = (float*)d_out;                  // [NN][32] persistent

    float* ws  = (float*)d_ws;
    float* u   = ws;                              // [NN][32]
    float* v   = u + (size_t)NN * 32;             // [NN][32]
    float* acc = v + (size_t)NN * 32;             // [NN][32]
    float* bg  = acc + (size_t)NN * 32;           // [128]
    float* W1p = bg + 128;                        // [128]
    u16* Wg_bf = (u16*)(W1p + 128);               // [128][64] bf16 (16B-aligned)
    u16* Wp_bf = Wg_bf + 8192;                    // [64][32] bf16
    int* bsum   = (int*)(Wp_bf + 2048);           // [256]
    int* boff   = bsum + 256;                     // [256]
    int* deg    = boff + 256;                     // [NN]
    int* rank   = deg + NN;                       // [NE2]
    int* rowptr = rank + NE2;                     // [NN+1]
    uintptr_t sp = (uintptr_t)(rowptr + NN + 1);
    sp = (sp + 255) & ~(uintptr_t)255;
    int2* sd = (int2*)sp;                         // [NE2] packed (s,d)

    const int* e0 = edges;
    const int* e1 = edges + NE;

    prep_kernel<<<41, 256, 0, stream>>>(Wih_n, Whh_n, bih_n, bhh_n, W1, b1,
                                        Wg_bf, bg, W1p, Wp_bf);
    hipMemsetAsync(deg, 0, (size_t)NN * sizeof(int), stream);
    hist_rank_kernel<<<NE2 / 256, 256, 0, stream>>>(e0, e1, deg, rank);
    scan_part_kernel<<<NBLK, 256, 0, stream>>>(deg, bsum);
    scan_mid_kernel<<<1, 256, 0, stream>>>(bsum, boff, rowptr);
    scan_apply_kernel<<<NBLK, 256, 0, stream>>>(deg, boff, rowptr);
    scatter_kernel<<<NE2 / 256, 256, 0, stream>>>(e0, e1, rowptr, rank, sd);
    init_kernel<<<NBLK, 256, 0, stream>>>(classes, W_in, b_in, W1,
                                          node, u, v, acc);
    for (int it = 0; it < 6; ++it) {
        edge_kernel<<<NE2 / 256, 256, 0, stream>>>(sd, pos, u, v, W1p,
                                                   W2, b2, W3, b3, acc);
        node_mfma_kernel<<<(NN + 63) / 64, 64, 0, stream>>>(node, acc, Wg_bf, bg,
                                                            Wp_bf, u, v, it == 5);
    }
}